// Round 6
// baseline (2977.199 us; speedup 1.0000x reference)
//
#include <hip/hip_runtime.h>
#include <math.h>

#define B_    32768
#define T_    128
#define OUT_  5
#define EPS_  1e-5f

typedef float f32x4 __attribute__((ext_vector_type(4)));
typedef __bf16 bfrag __attribute__((ext_vector_type(8)));
typedef unsigned short ushort_t;

// ---- workspace layout (float offsets) — R2/R5-proven 119184-float footprint ----
// Wc2:   ushort[33][8][4][16][8] = 135168 ushorts = 67584 floats (fragment-ordered:
//        tile T<32: rows g=16T+lm (g=gate*128+cell); T=32: z/w_out rows; k=ks*32+lq*8+e)
// gbias: [528]  b_ih+b_hh (g<512), b_out (512..516), 0
// A0/A1/C: [128][128] folded embed+BN coefficients
// istats:[128][5], zstats:[128][5][2]
#define WS_WC2   0
#define WS_GB    67584
#define WS_A0    68112
#define WS_A1    84496
#define WS_C     100880
#define WS_IST   117264
#define WS_ZST   117904

__device__ __forceinline__ ushort_t f2bf(float f) {  // RNE
  unsigned u = __float_as_uint(f);
  u += 0x7FFFu + ((u >> 16) & 1u);
  return (ushort_t)(u >> 16);
}
__device__ __forceinline__ float fsig(float x) {
  return __builtin_amdgcn_rcpf(1.f + __expf(-x));
}
__device__ __forceinline__ float ftanh(float x) {
  return 1.f - 2.f * __builtin_amdgcn_rcpf(1.f + __expf(2.f * x));
}

// ---- kernel 1: per-timestep input moments (verified) ----
__global__ void k_istats(const float* __restrict__ x, float* __restrict__ istats) {
  const int tid = threadIdx.x;
  const int t = tid >> 1;
  const int i = tid & 1;
  const long b0 = (long)blockIdx.x * 64;
  float s_v = 0.f, s_vv = 0.f, s_cross = 0.f;
  for (int s = 0; s < 64; ++s) {
    float v = x[(b0 + s) * 256 + tid];
    float p = __shfl_xor(v, 1);
    s_v += v; s_vv += v * v; s_cross += v * p;
  }
  float* st = istats + t * 5;
  if (i == 0) {
    atomicAdd(st + 0, s_v); atomicAdd(st + 2, s_vv); atomicAdd(st + 4, s_cross);
  } else {
    atomicAdd(st + 1, s_v); atomicAdd(st + 3, s_vv);
  }
}

// ---- kernel 2: pack weights to fragment-ordered bf16 Wc2 + gbias (verified) ----
__global__ void k_prep_w(const float* __restrict__ w_ih, const float* __restrict__ w_hh,
                         const float* __restrict__ w_out, const float* __restrict__ b_ih,
                         const float* __restrict__ b_hh, const float* __restrict__ b_out,
                         ushort_t* __restrict__ Wc2, float* __restrict__ gbias) {
  int idx = blockIdx.x * 256 + threadIdx.x;  // 0 .. 135167
  int e = idx & 7;
  int lm = (idx >> 3) & 15;
  int lq = (idx >> 7) & 3;
  int ks = (idx >> 9) & 7;
  int T = idx >> 12;
  int k = ks * 32 + lq * 8 + e;
  float v;
  if (T < 32) {
    int g = T * 16 + lm;  // row = gate*128 + cell
    v = (k < 128) ? w_ih[g * 128 + k] : w_hh[g * 128 + (k - 128)];
  } else {
    v = (k >= 128 && lm < OUT_) ? w_out[lm * 128 + (k - 128)] : 0.f;
  }
  Wc2[idx] = f2bf(v);
  if (idx < 528) {
    float bv = (idx < 512) ? b_ih[idx] + b_hh[idx]
                           : (idx < 517 ? b_out[idx - 512] : 0.f);
    gbias[idx] = bv;
  }
}

// ---- kernel 3: fold embed linear + BN into per-(t,f) affine coeffs (verified) ----
__global__ void k_coef(const float* __restrict__ istats, const float* __restrict__ w_emb,
                       const float* __restrict__ b_emb, const float* __restrict__ gamma1,
                       const float* __restrict__ beta1, float* __restrict__ A0,
                       float* __restrict__ A1, float* __restrict__ C) {
  int idx = blockIdx.x * 256 + threadIdx.x;  // 0 .. 16383
  int t = idx >> 7, f = idx & 127;
  const float* st = istats + t * 5;
  const float invB = 1.f / (float)B_;
  float m0 = st[0] * invB, m1 = st[1] * invB;
  float v00 = st[2] * invB - m0 * m0;
  float v11 = st[3] * invB - m1 * m1;
  float c01 = st[4] * invB - m0 * m1;
  float w0 = w_emb[f * 2 + 0], w1 = w_emb[f * 2 + 1];
  float mu = m0 * w0 + m1 * w1 + b_emb[f];
  float var = w0 * w0 * v00 + w1 * w1 * v11 + 2.f * w0 * w1 * c01;
  float alpha = gamma1[f] * rsqrtf(var + EPS_);
  A0[t * 128 + f] = alpha * w0;
  A1[t * 128 + f] = alpha * w1;
  C[t * 128 + f] = alpha * (b_emb[f] - mu) + beta1[f];
}

// ---- kernel 4: MFMA recurrent LSTM ----
// 256 blocks x 512 threads (8 waves), S=128 samples/block.
// Wave w owns gate tiles {w,w+8,w+16,w+24} = gates i,f,g,o of cells [16w,16w+16):
// elementwise is register-local.
// Weights: ks-chunks 0..3 (e-half) PERSISTENT in VGPRs (64 regs/wave, loaded once);
// chunks 4..7 (h-half) streamed global->VGPR with reg double-buffer + 4-phase
// block rotation. z written to LDS zbuf, flushed every 16 t as contiguous bursts.
__global__ __launch_bounds__(512, 2) void k_lstm(
    const float* __restrict__ x, const ushort_t* __restrict__ Wc2,
    const float* __restrict__ gbias, const float* __restrict__ A0,
    const float* __restrict__ A1, const float* __restrict__ Cc,
    float* __restrict__ out, float* __restrict__ zstats) {
  __shared__ __align__(16) ushort_t Abuf[128][272];  // 69.6 KB
  __shared__ __align__(16) float zbuf[128][84];      // 43 KB: z for 16-t groups
  __shared__ float zred[8][5], zred2[8][5];

  const int tid = threadIdx.x;
  const int w = tid >> 6;   // wave 0..7
  const int l = tid & 63;
  const int lm = l & 15;    // MFMA lane col
  const int lq = l >> 4;    // MFMA quad
  const long b0 = (long)blockIdx.x * 128;
  const int phase4 = blockIdx.x & 3;  // rotation among streamed chunks 4..7

  const uint4* W4 = (const uint4*)Wc2;  // frag(T,ks,lane) = W4[(T*8+ks)*64 + lane]
  int tb[4];
#pragma unroll
  for (int i = 0; i < 4; ++i) tb[i] = (w + 8 * i) * 8 * 64;

  // zero Abuf (h(-1)=0)
  for (int i = tid; i < 128 * 272 / 8; i += 512)
    ((uint4*)&Abuf[0][0])[i] = make_uint4(0u, 0u, 0u, 0u);

  float bias_g[4];
#pragma unroll
  for (int i = 0; i < 4; ++i) bias_g[i] = gbias[(w + 8 * i) * 16 + lm];
  const float bias_z = gbias[512 + lm];

  // persistent e-half weights: chunks 0..3 x 4 tiles (64 VGPRs)
  uint4 wp[4][4];
#pragma unroll
  for (int ks = 0; ks < 4; ++ks)
#pragma unroll
    for (int i = 0; i < 4; ++i) wp[ks][i] = W4[tb[i] + ks * 64 + l];

  // z-weight fragments (tile 32, chunks 4..7) persistent (16 VGPRs)
  uint4 wzf[4];
#pragma unroll
  for (int i = 0; i < 4; ++i) wzf[i] = W4[(32 * 8 + 4 + i) * 64 + l];

  // e-staging roles: row em, 16B chunk ec
  const int em = (w << 4) + (l >> 2);
  const int ec = l & 3;
  const float2* x2 = (const float2*)x;

  float cst[8][4];
#pragma unroll
  for (int mt = 0; mt < 8; ++mt)
#pragma unroll
    for (int r = 0; r < 4; ++r) cst[mt][r] = 0.f;

  // preload first streamed chunk (index 4+phase4) into buffer 0
  uint4 wb[2][4];
#pragma unroll
  for (int i = 0; i < 4; ++i) wb[0][i] = W4[tb[i] + (4 + phase4) * 64 + l];

  __syncthreads();  // Abuf zero visible

  for (int t = 0; t <= T_; ++t) {
    // ---- stage e(t) ----
    if (t < T_) {
      float2 xv = x2[(size_t)(b0 + em) * 128 + t];
#pragma unroll
      for (int p = 0; p < 4; ++p) {
        const int f0 = p * 32 + ec * 8;
        const f32x4 a0l = *(const f32x4*)(A0 + t * 128 + f0);
        const f32x4 a0h = *(const f32x4*)(A0 + t * 128 + f0 + 4);
        const f32x4 a1l = *(const f32x4*)(A1 + t * 128 + f0);
        const f32x4 a1h = *(const f32x4*)(A1 + t * 128 + f0 + 4);
        const f32x4 ccl = *(const f32x4*)(Cc + t * 128 + f0);
        const f32x4 cch = *(const f32x4*)(Cc + t * 128 + f0 + 4);
        unsigned pk[4];
#pragma unroll
        for (int h2 = 0; h2 < 4; ++h2) {
          float e0, e1;
          if (h2 < 2) {
            e0 = fmaf(xv.x, a0l[h2 * 2], fmaf(xv.y, a1l[h2 * 2], ccl[h2 * 2]));
            e1 = fmaf(xv.x, a0l[h2 * 2 + 1], fmaf(xv.y, a1l[h2 * 2 + 1], ccl[h2 * 2 + 1]));
          } else {
            e0 = fmaf(xv.x, a0h[(h2 - 2) * 2], fmaf(xv.y, a1h[(h2 - 2) * 2], cch[(h2 - 2) * 2]));
            e1 = fmaf(xv.x, a0h[(h2 - 2) * 2 + 1],
                      fmaf(xv.y, a1h[(h2 - 2) * 2 + 1], cch[(h2 - 2) * 2 + 1]));
          }
          e0 = fmaxf(e0, 0.f); e1 = fmaxf(e1, 0.f);
          pk[h2] = (unsigned)f2bf(e0) | ((unsigned)f2bf(e1) << 16);
        }
        *(uint4*)&Abuf[em][f0] = make_uint4(pk[0], pk[1], pk[2], pk[3]);
      }
    }
    __syncthreads();  // B1: e(t) + h(t-1) ready

    // ---- MFMA gate pass ----
    f32x4 acc[8][4];
#pragma unroll
    for (int mt = 0; mt < 8; ++mt)
#pragma unroll
      for (int i = 0; i < 4; ++i) {
        f32x4 v = {bias_g[i], bias_g[i], bias_g[i], bias_g[i]};
        acc[mt][i] = v;
      }

    // persistent chunks 0..3 (e-half) — no global traffic
#pragma unroll
    for (int ks = 0; ks < 4; ++ks) {
      bfrag Bf[4];
#pragma unroll
      for (int i = 0; i < 4; ++i) Bf[i] = __builtin_bit_cast(bfrag, wp[ks][i]);
#pragma unroll
      for (int mt = 0; mt < 8; ++mt) {
        bfrag Af = __builtin_bit_cast(bfrag, *(const uint4*)&Abuf[mt * 16 + lm][ks * 32 + lq * 8]);
#pragma unroll
        for (int i = 0; i < 4; ++i)
          acc[mt][i] = __builtin_amdgcn_mfma_f32_16x16x32_bf16(Af, Bf[i], acc[mt][i], 0, 0, 0);
      }
    }
    // streamed chunks 4..7 (h-half), rotated start, reg double-buffer
#pragma unroll
    for (int kk = 0; kk < 4; ++kk) {
      const int p = kk & 1;
      const int ks = 4 + ((phase4 + kk) & 3);
      const int ksn = 4 + ((phase4 + kk + 1) & 3);
#pragma unroll
      for (int i = 0; i < 4; ++i) wb[p ^ 1][i] = W4[tb[i] + ksn * 64 + l];
      bfrag Bf[4];
#pragma unroll
      for (int i = 0; i < 4; ++i) Bf[i] = __builtin_bit_cast(bfrag, wb[p][i]);
#pragma unroll
      for (int mt = 0; mt < 8; ++mt) {
        bfrag Af = __builtin_bit_cast(bfrag, *(const uint4*)&Abuf[mt * 16 + lm][ks * 32 + lq * 8]);
#pragma unroll
        for (int i = 0; i < 4; ++i)
          acc[mt][i] = __builtin_amdgcn_mfma_f32_16x16x32_bf16(Af, Bf[i], acc[mt][i], 0, 0, 0);
      }
    }

    // ---- z(t-1) = h(t-1) @ w_out^T: persistent wzf, chunks 4..7 ----
    f32x4 zac = {bias_z, bias_z, bias_z, bias_z};
#pragma unroll
    for (int i = 0; i < 4; ++i) {
      bfrag Af = __builtin_bit_cast(bfrag, *(const uint4*)&Abuf[w * 16 + lm][(4 + i) * 32 + lq * 8]);
      zac = __builtin_amdgcn_mfma_f32_16x16x32_bf16(Af, __builtin_bit_cast(bfrag, wzf[i]), zac, 0, 0, 0);
    }

    // ---- z(t-1): LDS-buffer + wave-partial stats ----
    if (t > 0) {
      float sz = 0.f, sq = 0.f;
      const int ts = ((t - 1) & 15) * 5;
#pragma unroll
      for (int r = 0; r < 4; ++r) {
        float zv = zac[r];
        if (lm < OUT_) zbuf[(w << 4) + lq * 4 + r][ts + lm] = zv;
        sz += zv; sq += zv * zv;
      }
      sz += __shfl_xor(sz, 16); sz += __shfl_xor(sz, 32);
      sq += __shfl_xor(sq, 16); sq += __shfl_xor(sq, 32);
      if (lq == 0 && lm < OUT_) { zred[w][lm] = sz; zred2[w][lm] = sq; }
    }
    __syncthreads();  // B2: Abuf reads + zbuf writes done; zred ready

    if (t > 0 && tid < 10) {
      int o = tid >> 1, kind = tid & 1;
      float s = 0.f;
#pragma unroll
      for (int ww = 0; ww < 8; ++ww) s += kind ? zred2[ww][o] : zred[ww][o];
      atomicAdd(&zstats[(size_t)(t - 1) * 10 + o * 2 + kind], s);
    }

    // ---- flush zbuf every 16 t: contiguous 320 B/sample, full-line dirty ----
    if (t >= 16 && (t & 15) == 0) {
      const int sid = tid >> 2, part = tid & 3;
      const int tg = t - 16;
      float* dst = out + (size_t)(b0 + sid) * (T_ * OUT_) + tg * OUT_ + part * 20;
      const float* src = &zbuf[sid][part * 20];
#pragma unroll
      for (int j = 0; j < 5; ++j)
        *(f32x4*)(dst + 4 * j) = *(const f32x4*)(src + 4 * j);
    }
    // next group's zbuf writes happen after the NEXT B1 -> no race with this flush.

    // ---- elementwise LSTM: register-local gates -> h(t) into Abuf ----
    if (t < T_) {
#pragma unroll
      for (int mt = 0; mt < 8; ++mt) {
#pragma unroll
        for (int r = 0; r < 4; ++r) {
          float gi = acc[mt][0][r], gf = acc[mt][1][r];
          float gg = acc[mt][2][r], go = acc[mt][3][r];
          float ig = fsig(gi), fg = fsig(gf), g2 = ftanh(gg), og = fsig(go);
          float cn = fmaf(fg, cst[mt][r], ig * g2);
          cst[mt][r] = cn;
          float h = og * ftanh(cn);
          Abuf[mt * 16 + lq * 4 + r][128 + (w << 4) + lm] = f2bf(h);
        }
      }
    }
  }
}

// ---- kernel 5: in-place output BN + ReLU (verified) ----
__global__ void k_outbn(float* __restrict__ out, const float* __restrict__ zstats,
                        const float* __restrict__ gamma2, const float* __restrict__ beta2) {
  int idx = blockIdx.x * 256 + threadIdx.x;
  int r = idx % 640;
  int t = r / 5, o = r - t * 5;
  float z = out[idx];
  float sum = zstats[t * 10 + o * 2];
  float ss = zstats[t * 10 + o * 2 + 1];
  float mu = sum * (1.f / (float)B_);
  float var = ss * (1.f / (float)B_) - mu * mu;
  float y = gamma2[o] * (z - mu) * rsqrtf(var + EPS_) + beta2[o];
  out[idx] = fmaxf(y, 0.f);
}

extern "C" void kernel_launch(void* const* d_in, const int* in_sizes, int n_in, void* d_out,
                              int out_size, void* d_ws, size_t ws_size, hipStream_t stream) {
  const float* x = (const float*)d_in[0];
  const float* w_emb = (const float*)d_in[1];
  const float* b_emb = (const float*)d_in[2];
  const float* gamma1 = (const float*)d_in[3];
  const float* beta1 = (const float*)d_in[4];
  const float* w_ih = (const float*)d_in[5];
  const float* w_hh = (const float*)d_in[6];
  const float* b_ih = (const float*)d_in[7];
  const float* b_hh = (const float*)d_in[8];
  const float* w_out = (const float*)d_in[9];
  const float* b_out = (const float*)d_in[10];
  const float* gamma2 = (const float*)d_in[11];
  const float* beta2 = (const float*)d_in[12];
  float* out = (float*)d_out;
  float* ws = (float*)d_ws;

  ushort_t* Wc2 = (ushort_t*)(ws + WS_WC2);
  float* gbias = ws + WS_GB;
  float* A0 = ws + WS_A0;
  float* A1 = ws + WS_A1;
  float* C = ws + WS_C;
  float* istats = ws + WS_IST;
  float* zstats = ws + WS_ZST;

  hipMemsetAsync(istats, 0, 640 * sizeof(float), stream);
  hipMemsetAsync(zstats, 0, 1280 * sizeof(float), stream);

  k_istats<<<512, 256, 0, stream>>>(x, istats);
  k_prep_w<<<528, 256, 0, stream>>>(w_ih, w_hh, w_out, b_ih, b_hh, b_out, Wc2, gbias);
  k_coef<<<64, 256, 0, stream>>>(istats, w_emb, b_emb, gamma1, beta1, A0, A1, C);
  k_lstm<<<256, 512, 0, stream>>>(x, Wc2, gbias, A0, A1, C, out, zstats);
  k_outbn<<<(B_ * T_ * OUT_) / 256, 256, 0, stream>>>(out, zstats, gamma2, beta2);
}

// Round 8
// 2821.646 us; speedup vs baseline: 1.0551x; 1.0551x over previous
//
#include <hip/hip_runtime.h>
#include <math.h>

#define B_    32768
#define T_    128
#define OUT_  5
#define EPS_  1e-5f

typedef float f32x4 __attribute__((ext_vector_type(4)));
typedef __bf16 bfrag __attribute__((ext_vector_type(8)));
typedef unsigned short ushort_t;

// ---- workspace layout (float offsets) ----
// Wc2: ushort[260][64][8] = 133120 ushorts = 66560 floats, CONTIGUOUS-STREAM order:
//      frag f<256: f = ks*32 + w*4 + i  (chunk ks 0..7, wave w 0..7, tile-slot i 0..3)
//        -> tile T = w + 8*i (gate i of cell group w), rows g = 16T+lm, k = ks*32+lq*8+e
//      At chunk ks a block's 8 waves read ONE contiguous 32 KB region (wave w: 4 KB).
//      frag 256..259: z/w_out frags for h-chunks 4..7.
// gbias: [528]  b_ih+b_hh (g<512), b_out (512..516), 0
// A0/A1/C: [128][128] folded embed+BN coefficients
// istats:[128][5], zstats:[128][5][2]   (total 118160 floats, within proven bound)
#define WS_WC2   0
#define WS_GB    66560
#define WS_A0    67088
#define WS_A1    83472
#define WS_C     99856
#define WS_IST   116240
#define WS_ZST   116880

__device__ __forceinline__ ushort_t f2bf(float f) {  // RNE
  unsigned u = __float_as_uint(f);
  u += 0x7FFFu + ((u >> 16) & 1u);
  return (ushort_t)(u >> 16);
}
__device__ __forceinline__ float fsig(float x) {
  return __builtin_amdgcn_rcpf(1.f + __expf(-x));
}
__device__ __forceinline__ float ftanh(float x) {
  return 1.f - 2.f * __builtin_amdgcn_rcpf(1.f + __expf(2.f * x));
}

// ---- kernel 1: per-timestep input moments (verified) ----
__global__ void k_istats(const float* __restrict__ x, float* __restrict__ istats) {
  const int tid = threadIdx.x;
  const int t = tid >> 1;
  const int i = tid & 1;
  const long b0 = (long)blockIdx.x * 64;
  float s_v = 0.f, s_vv = 0.f, s_cross = 0.f;
  for (int s = 0; s < 64; ++s) {
    float v = x[(b0 + s) * 256 + tid];
    float p = __shfl_xor(v, 1);
    s_v += v; s_vv += v * v; s_cross += v * p;
  }
  float* st = istats + t * 5;
  if (i == 0) {
    atomicAdd(st + 0, s_v); atomicAdd(st + 2, s_vv); atomicAdd(st + 4, s_cross);
  } else {
    atomicAdd(st + 1, s_v); atomicAdd(st + 3, s_vv);
  }
}

// ---- kernel 2: pack weights, contiguous-stream order ----
__global__ void k_prep_w(const float* __restrict__ w_ih, const float* __restrict__ w_hh,
                         const float* __restrict__ w_out, const float* __restrict__ b_ih,
                         const float* __restrict__ b_hh, const float* __restrict__ b_out,
                         ushort_t* __restrict__ Wc2, float* __restrict__ gbias) {
  int idx = blockIdx.x * 256 + threadIdx.x;  // 0 .. 133119
  int e = idx & 7;
  int q = idx >> 3;   // uint4 index
  int l = q & 63;
  int f = q >> 6;     // frag id 0..259
  int lm = l & 15, lq = (l >> 4) & 3;
  float v;
  if (f < 256) {
    int i = f & 3, w = (f >> 2) & 7, ks = f >> 5;
    int T = w + 8 * i;
    int g = T * 16 + lm;               // row = gate*128 + cell
    int k = ks * 32 + lq * 8 + e;
    v = (k < 128) ? w_ih[g * 128 + k] : w_hh[g * 128 + (k - 128)];
  } else {
    int zi = f - 256;                  // h-chunk 4+zi
    int k = (4 + zi) * 32 + lq * 8 + e;  // 128..255
    v = (lm < OUT_) ? w_out[lm * 128 + (k - 128)] : 0.f;
  }
  Wc2[idx] = f2bf(v);
  if (idx < 528) {
    float bv = (idx < 512) ? b_ih[idx] + b_hh[idx]
                           : (idx < 517 ? b_out[idx - 512] : 0.f);
    gbias[idx] = bv;
  }
}

// ---- kernel 3: fold embed linear + BN into per-(t,f) affine coeffs (verified) ----
__global__ void k_coef(const float* __restrict__ istats, const float* __restrict__ w_emb,
                       const float* __restrict__ b_emb, const float* __restrict__ gamma1,
                       const float* __restrict__ beta1, float* __restrict__ A0,
                       float* __restrict__ A1, float* __restrict__ C) {
  int idx = blockIdx.x * 256 + threadIdx.x;  // 0 .. 16383
  int t = idx >> 7, f = idx & 127;
  const float* st = istats + t * 5;
  const float invB = 1.f / (float)B_;
  float m0 = st[0] * invB, m1 = st[1] * invB;
  float v00 = st[2] * invB - m0 * m0;
  float v11 = st[3] * invB - m1 * m1;
  float c01 = st[4] * invB - m0 * m1;
  float w0 = w_emb[f * 2 + 0], w1 = w_emb[f * 2 + 1];
  float mu = m0 * w0 + m1 * w1 + b_emb[f];
  float var = w0 * w0 * v00 + w1 * w1 * v11 + 2.f * w0 * w1 * c01;
  float alpha = gamma1[f] * rsqrtf(var + EPS_);
  A0[t * 128 + f] = alpha * w0;
  A1[t * 128 + f] = alpha * w1;
  C[t * 128 + f] = alpha * (b_emb[f] - mu) + beta1[f];
}

// ---- kernel 4: MFMA recurrent LSTM (R5 structure, contiguous weight stream) ----
// 256 blocks x 512 threads (8 waves), S=128 samples/block.
// Wave w owns gate tiles {w,w+8,w+16,w+24} = gates i,f,g,o of cells [16w,16w+16):
// elementwise is register-local. Weights: global->VGPR reg double-buffer,
// per-block phase rotation; at chunk ks the block reads ONE contiguous 32 KB.
__global__ __launch_bounds__(512, 2) void k_lstm(
    const float* __restrict__ x, const ushort_t* __restrict__ Wc2,
    const float* __restrict__ gbias, const float* __restrict__ A0,
    const float* __restrict__ A1, const float* __restrict__ Cc,
    float* __restrict__ out, float* __restrict__ zstats) {
  __shared__ __align__(16) ushort_t Abuf[128][272];  // 69.6 KB
  __shared__ float zred[8][5], zred2[8][5];

  const int tid = threadIdx.x;
  const int w = tid >> 6;   // wave 0..7
  const int l = tid & 63;
  const int lm = l & 15;    // MFMA lane col
  const int lq = l >> 4;    // MFMA quad
  const long b0 = (long)blockIdx.x * 128;
  const int phase = blockIdx.x & 7;  // chunk-rotation phase (desync across blocks)

  const uint4* W4 = (const uint4*)Wc2;  // frag(ks,w,i) at W4[(ks*32 + w*4 + i)*64 + l]

  // zero Abuf (h(-1)=0)
  for (int i = tid; i < 128 * 272 / 8; i += 512)
    ((uint4*)&Abuf[0][0])[i] = make_uint4(0u, 0u, 0u, 0u);

  float bias_g[4];
#pragma unroll
  for (int i = 0; i < 4; ++i) bias_g[i] = gbias[(w + 8 * i) * 16 + lm];
  const float bias_z = gbias[512 + lm];

  // z-weight fragments (h-chunks 4..7): frags 256..259, tail of Wc2
  uint4 wzf[4];
#pragma unroll
  for (int i = 0; i < 4; ++i) wzf[i] = W4[(256 + i) * 64 + l];

  // e-staging roles: row em, 16B chunk ec
  const int em = (w << 4) + (l >> 2);
  const int ec = l & 3;
  const float2* x2 = (const float2*)x;

  float cst[8][4];
#pragma unroll
  for (int mt = 0; mt < 8; ++mt)
#pragma unroll
    for (int r = 0; r < 4; ++r) cst[mt][r] = 0.f;

  // preload first weight chunk (index = phase) into buffer 0
  uint4 wb[2][4];
#pragma unroll
  for (int i = 0; i < 4; ++i) wb[0][i] = W4[((phase * 8 + w) * 4 + i) * 64 + l];

  __syncthreads();  // Abuf zero visible

  for (int t = 0; t <= T_; ++t) {
    // ---- stage e(t) ----
    if (t < T_) {
      float2 xv = x2[(size_t)(b0 + em) * 128 + t];
#pragma unroll
      for (int p = 0; p < 4; ++p) {
        const int f0 = p * 32 + ec * 8;
        const f32x4 a0l = *(const f32x4*)(A0 + t * 128 + f0);
        const f32x4 a0h = *(const f32x4*)(A0 + t * 128 + f0 + 4);
        const f32x4 a1l = *(const f32x4*)(A1 + t * 128 + f0);
        const f32x4 a1h = *(const f32x4*)(A1 + t * 128 + f0 + 4);
        const f32x4 ccl = *(const f32x4*)(Cc + t * 128 + f0);
        const f32x4 cch = *(const f32x4*)(Cc + t * 128 + f0 + 4);
        unsigned pk[4];
#pragma unroll
        for (int h2 = 0; h2 < 4; ++h2) {
          float e0, e1;
          if (h2 < 2) {
            e0 = fmaf(xv.x, a0l[h2 * 2], fmaf(xv.y, a1l[h2 * 2], ccl[h2 * 2]));
            e1 = fmaf(xv.x, a0l[h2 * 2 + 1], fmaf(xv.y, a1l[h2 * 2 + 1], ccl[h2 * 2 + 1]));
          } else {
            e0 = fmaf(xv.x, a0h[(h2 - 2) * 2], fmaf(xv.y, a1h[(h2 - 2) * 2], cch[(h2 - 2) * 2]));
            e1 = fmaf(xv.x, a0h[(h2 - 2) * 2 + 1],
                      fmaf(xv.y, a1h[(h2 - 2) * 2 + 1], cch[(h2 - 2) * 2 + 1]));
          }
          e0 = fmaxf(e0, 0.f); e1 = fmaxf(e1, 0.f);
          pk[h2] = (unsigned)f2bf(e0) | ((unsigned)f2bf(e1) << 16);
        }
        *(uint4*)&Abuf[em][f0] = make_uint4(pk[0], pk[1], pk[2], pk[3]);
      }
    }
    __syncthreads();  // B1: e(t) + h(t-1) ready

    // ---- MFMA gate pass: 8 k-chunks, rotated start, reg double-buffer ----
    f32x4 acc[8][4];
#pragma unroll
    for (int mt = 0; mt < 8; ++mt)
#pragma unroll
      for (int i = 0; i < 4; ++i) {
        f32x4 v = {bias_g[i], bias_g[i], bias_g[i], bias_g[i]};
        acc[mt][i] = v;
      }

    int ks = phase;
#pragma unroll
    for (int kk = 0; kk < 8; ++kk) {
      const int p = kk & 1;
      const int ksn = (ks + 1) & 7;
      // prefetch next chunk (at kk=7 this reloads chunk `phase` for the next t)
#pragma unroll
      for (int i = 0; i < 4; ++i) wb[p ^ 1][i] = W4[((ksn * 8 + w) * 4 + i) * 64 + l];
      bfrag Bf[4];
#pragma unroll
      for (int i = 0; i < 4; ++i) Bf[i] = __builtin_bit_cast(bfrag, wb[p][i]);
#pragma unroll
      for (int mt = 0; mt < 8; ++mt) {
        bfrag Af = __builtin_bit_cast(bfrag, *(const uint4*)&Abuf[mt * 16 + lm][ks * 32 + lq * 8]);
#pragma unroll
        for (int i = 0; i < 4; ++i)
          acc[mt][i] = __builtin_amdgcn_mfma_f32_16x16x32_bf16(Af, Bf[i], acc[mt][i], 0, 0, 0);
      }
      ks = ksn;
    }

    // ---- z(t-1) = h(t-1) @ w_out^T: persistent wzf, h-chunks 4..7 ----
    f32x4 zac = {bias_z, bias_z, bias_z, bias_z};
#pragma unroll
    for (int i = 0; i < 4; ++i) {
      bfrag Af = __builtin_bit_cast(bfrag, *(const uint4*)&Abuf[w * 16 + lm][(4 + i) * 32 + lq * 8]);
      zac = __builtin_amdgcn_mfma_f32_16x16x32_bf16(Af, __builtin_bit_cast(bfrag, wzf[i]), zac, 0, 0, 0);
    }

    // ---- z(t-1): store raw + wave-partial stats ----
    if (t > 0) {
      float sz = 0.f, sq = 0.f;
#pragma unroll
      for (int r = 0; r < 4; ++r) {
        float zv = zac[r];
        if (lm < OUT_)
          out[(size_t)(b0 + (w << 4) + lq * 4 + r) * (T_ * OUT_) + (size_t)(t - 1) * OUT_ + lm] = zv;
        sz += zv; sq += zv * zv;
      }
      sz += __shfl_xor(sz, 16); sz += __shfl_xor(sz, 32);
      sq += __shfl_xor(sq, 16); sq += __shfl_xor(sq, 32);
      if (lq == 0 && lm < OUT_) { zred[w][lm] = sz; zred2[w][lm] = sq; }
    }
    __syncthreads();  // B2: Abuf reads done; zred ready

    if (t > 0 && tid < 10) {
      int o = tid >> 1, kind = tid & 1;
      float s = 0.f;
#pragma unroll
      for (int ww = 0; ww < 8; ++ww) s += kind ? zred2[ww][o] : zred[ww][o];
      atomicAdd(&zstats[(size_t)(t - 1) * 10 + o * 2 + kind], s);
    }

    // ---- elementwise LSTM: register-local gates -> h(t) into Abuf ----
    if (t < T_) {
#pragma unroll
      for (int mt = 0; mt < 8; ++mt) {
#pragma unroll
        for (int r = 0; r < 4; ++r) {
          float gi = acc[mt][0][r], gf = acc[mt][1][r];
          float gg = acc[mt][2][r], go = acc[mt][3][r];
          float ig = fsig(gi), fg = fsig(gf), g2 = ftanh(gg), og = fsig(go);
          float cn = fmaf(fg, cst[mt][r], ig * g2);
          cst[mt][r] = cn;
          float h = og * ftanh(cn);
          Abuf[mt * 16 + lq * 4 + r][128 + (w << 4) + lm] = f2bf(h);
        }
      }
    }
  }
}

// ---- kernel 5: in-place output BN + ReLU (verified) ----
__global__ void k_outbn(float* __restrict__ out, const float* __restrict__ zstats,
                        const float* __restrict__ gamma2, const float* __restrict__ beta2) {
  int idx = blockIdx.x * 256 + threadIdx.x;
  int r = idx % 640;
  int t = r / 5, o = r - t * 5;
  float z = out[idx];
  float sum = zstats[t * 10 + o * 2];
  float ss = zstats[t * 10 + o * 2 + 1];
  float mu = sum * (1.f / (float)B_);
  float var = ss * (1.f / (float)B_) - mu * mu;
  float y = gamma2[o] * (z - mu) * rsqrtf(var + EPS_) + beta2[o];
  out[idx] = fmaxf(y, 0.f);
}

extern "C" void kernel_launch(void* const* d_in, const int* in_sizes, int n_in, void* d_out,
                              int out_size, void* d_ws, size_t ws_size, hipStream_t stream) {
  const float* x = (const float*)d_in[0];
  const float* w_emb = (const float*)d_in[1];
  const float* b_emb = (const float*)d_in[2];
  const float* gamma1 = (const float*)d_in[3];
  const float* beta1 = (const float*)d_in[4];
  const float* w_ih = (const float*)d_in[5];
  const float* w_hh = (const float*)d_in[6];
  const float* b_ih = (const float*)d_in[7];
  const float* b_hh = (const float*)d_in[8];
  const float* w_out = (const float*)d_in[9];
  const float* b_out = (const float*)d_in[10];
  const float* gamma2 = (const float*)d_in[11];
  const float* beta2 = (const float*)d_in[12];
  float* out = (float*)d_out;
  float* ws = (float*)d_ws;

  ushort_t* Wc2 = (ushort_t*)(ws + WS_WC2);
  float* gbias = ws + WS_GB;
  float* A0 = ws + WS_A0;
  float* A1 = ws + WS_A1;
  float* C = ws + WS_C;
  float* istats = ws + WS_IST;
  float* zstats = ws + WS_ZST;

  hipMemsetAsync(istats, 0, 640 * sizeof(float), stream);
  hipMemsetAsync(zstats, 0, 1280 * sizeof(float), stream);

  k_istats<<<512, 256, 0, stream>>>(x, istats);
  k_prep_w<<<520, 256, 0, stream>>>(w_ih, w_hh, w_out, b_ih, b_hh, b_out, Wc2, gbias);
  k_coef<<<64, 256, 0, stream>>>(istats, w_emb, b_emb, gamma1, beta1, A0, A1, C);
  k_lstm<<<256, 512, 0, stream>>>(x, Wc2, gbias, A0, A1, C, out, zstats);
  k_outbn<<<(B_ * T_ * OUT_) / 256, 256, 0, stream>>>(out, zstats, gamma2, beta2);
}